// Round 2
// baseline (286.249 us; speedup 1.0000x reference)
//
#include <hip/hip_runtime.h>

// LightGCN 3-stage propagation — round 9: oct-structured SpMM (8 lanes/edge,
// dwordx2 gathers, packed f32x2 accumulate, byte-offset columns).
//
// Evidence trail:
//  r1: edge atomics -> 819MB/stage write-through (666us/stage).
//  r2: fine CSR spmm ~280us/stage (f32); scattered CSR build 297us.
//  r3: LDS-tile spmm latency-starved; coarse bucket build fast.
//  r4: bucket->LDS->CSR + wave-per-row bf16 spmm: 152us/stage.
//  r5: 16-edge batched gathers + prescaled state: 67us/stage (byte-bound).
//  r6: fp8 e4m3 state: 51us/stage.
//  r7: fused build + padded 8-aligned CSR with sentinel row: 278us total.
//  r8: unified strided spmm loop + wave scans in build: 261us total.
//      spmm counters: 41.5us/stage, VALU 58%, HBM 29%, occ 63% -> VALU-issue
//      bound (~2.2 instr/edge), HBM floor is 15us.
//  r9: (a) cols stored as byte offsets (col*64): addr = 1 v_add vs shl+add;
//      (b) 8 lanes/edge x dwordx2: halves gather instrs per byte;
//      (c) f32x2 packed accumulate (v_pk_add_f32): halves the add count.
//      Net ~1.34 instr/edge (cvt+add floor is 1.0).

constexpr int DIM = 64;
constexpr int ROWS_PER_BKT = 256;
constexpr int BKT_CAP = 11264;      // raw max ~8.7k + pad up to 256*7 -> 10.5k
constexpr int CHUNK = 4096;
constexpr int SCAN_N = 512;

using f32x2 = __attribute__((ext_vector_type(2))) float;

__device__ inline unsigned int pk_fp8_4(float a, float b, float c, float d) {
    int v = __builtin_amdgcn_cvt_pk_fp8_f32(a, b, 0, false);
    v = __builtin_amdgcn_cvt_pk_fp8_f32(c, d, v, true);
    return (unsigned int)v;
}

// Block-aggregated coarse scatter into 391 row-buckets (512 threads,
// 8 edges/thread). Ranks relative to cursor[]==0 (memset).
__global__ __launch_bounds__(512) void scatter_agg(
        const int4* __restrict__ row4, const int4* __restrict__ col4,
        int* __restrict__ cursor, unsigned int* __restrict__ ebuf,
        int num_edges, int nb) {
    __shared__ unsigned int cnt[SCAN_N];
    __shared__ unsigned int orig[SCAN_N];
    __shared__ unsigned int bbase[SCAN_N];
    __shared__ unsigned int wsum[8];
    __shared__ unsigned int stage[CHUNK];
    __shared__ unsigned int dsts[CHUNK];
    const int t = threadIdx.x;

    cnt[t] = 0;
    __syncthreads();

    unsigned int pk[8];
    unsigned short bk[8], rk[8];
    const int base4 = blockIdx.x * (CHUNK / 4);
#pragma unroll
    for (int k = 0; k < 2; ++k) {
        int e4 = base4 + k * 512 + t;            // num_edges % 4 == 0
        if (e4 * 4 < num_edges) {
            int4 rr = row4[e4];
            int4 cc = col4[e4];
            int rs[4] = {rr.x, rr.y, rr.z, rr.w};
            int cs[4] = {cc.x, cc.y, cc.z, cc.w};
#pragma unroll
            for (int m = 0; m < 4; ++m) {
                int b = rs[m] >> 8;
                unsigned int rank = atomicAdd(&cnt[b], 1u);
                pk[k * 4 + m] = ((unsigned)(rs[m] & 255) << 17) | (unsigned)cs[m];
                bk[k * 4 + m] = (unsigned short)b;
                rk[k * 4 + m] = (unsigned short)rank;
            }
        } else {
#pragma unroll
            for (int m = 0; m < 4; ++m) bk[k * 4 + m] = 0xFFFFu;
        }
    }
    __syncthreads();

    // wave-level inclusive scan of cnt[] (2 barriers total)
    unsigned int myv = cnt[t];
    orig[t] = myv;
    unsigned int v = myv;
#pragma unroll
    for (int off = 1; off < 64; off <<= 1) {
        unsigned int nv = __shfl_up(v, off);
        if ((t & 63) >= off) v += nv;
    }
    if ((t & 63) == 63) wsum[t >> 6] = v;
    // per-bucket global base: independent of the scan, issue now
    if (t < nb && myv > 0)
        bbase[t] = (unsigned int)(t * BKT_CAP +
                                  atomicAdd(&cursor[t], (int)myv));
    __syncthreads();
    {
        unsigned int addv = 0;
        const int wid = t >> 6;
#pragma unroll
        for (int w = 0; w < 7; ++w)
            if (w < wid) addv += wsum[w];
        cnt[t] = v + addv;                       // inclusive scan result
    }
    __syncthreads();

#pragma unroll
    for (int k = 0; k < 8; ++k) {
        if (bk[k] != 0xFFFFu) {
            int b = bk[k];
            unsigned int ofs = (cnt[b] - orig[b]) + rk[k];
            stage[ofs] = pk[k];
            dsts[ofs] = bbase[b] + rk[k];
        }
    }
    __syncthreads();
    unsigned int total = cnt[SCAN_N - 1];
    for (unsigned int j = t; j < total; j += 512)
        ebuf[dsts[j]] = stage[j];
}

// One 512-thread block per bucket: hist -> padded scan -> permute into
// 8-aligned padded CSR (pad slots = sentinel node) -> coalesced write-out.
// col_fine now stores BYTE offsets (col*64) for the fp8 state gather.
// FUSED epilogue: init acc/emb0/curA for this bucket's 256 rows using the
// in-LDS degrees.
__global__ __launch_bounds__(512) void bucket_to_csr(
        const unsigned int* __restrict__ ebuf, const int* __restrict__ cursor,
        unsigned int* __restrict__ col_fine,
        int* __restrict__ row_start, int* __restrict__ row_end,
        float* __restrict__ dinv,
        const float* __restrict__ user_emb, const float* __restrict__ item_emb,
        float* __restrict__ acc_out, float* __restrict__ emb0_out,
        unsigned int* __restrict__ curA, unsigned int* __restrict__ curB,
        int n_user_elems, int n_total_elems, int n_rows, unsigned int sent) {
    __shared__ unsigned int hist[ROWS_PER_BKT];
    __shared__ unsigned int scanv[ROWS_PER_BKT];
    __shared__ unsigned int curl[ROWS_PER_BKT];
    __shared__ unsigned int wsumB[4];
    __shared__ unsigned int sorted[BKT_CAP];
    const int t = threadIdx.x;
    const int b = blockIdx.x;
    const int s = b * BKT_CAP;
    const int n = cursor[b];

    if (t < ROWS_PER_BKT) hist[t] = 0;
    __syncthreads();
    for (int j = t; j < n; j += 512)
        atomicAdd(&hist[ebuf[s + j] >> 17], 1u);
    __syncthreads();

    // wave-level inclusive scan of padded degrees (2 barriers total)
    unsigned int pdeg = 0;
    if (t < ROWS_PER_BKT) pdeg = (hist[t] + 7u) & ~7u;
    unsigned int v = pdeg;
#pragma unroll
    for (int off = 1; off < 64; off <<= 1) {
        unsigned int nv = __shfl_up(v, off);
        if ((t & 63) >= off) v += nv;
    }
    if (t < ROWS_PER_BKT && (t & 63) == 63) wsumB[t >> 6] = v;
    __syncthreads();
    if (t < ROWS_PER_BKT) {
        unsigned int addv = 0;
        const int wid = t >> 6;
#pragma unroll
        for (int w = 0; w < 3; ++w)
            if (w < wid) addv += wsumB[w];
        unsigned int incl = v + addv;
        scanv[t] = incl;
        unsigned int excl = incl - pdeg;
        curl[t] = excl;
        int r = b * ROWS_PER_BKT + t;
        if (r < n_rows) {
            unsigned int deg = hist[t];
            dinv[r] = 1.0f / sqrtf((float)(deg ? deg : 1u));
            row_start[r] = s + (int)excl;
            row_end[r]   = s + (int)(excl + pdeg);
        }
    }
    __syncthreads();
    unsigned int n_pad = scanv[ROWS_PER_BKT - 1];
    // prefill pad slots with sentinel byte offset
    const unsigned int sentb = sent << 6;
    for (unsigned int j = t; j < n_pad; j += 512) sorted[j] = sentb;
    __syncthreads();
    for (int j = t; j < n; j += 512) {
        unsigned int pk = ebuf[s + j];
        unsigned int p = atomicAdd(&curl[pk >> 17], 1u);
        sorted[p] = (pk & 0x1FFFFu) << 6;        // byte offset of fp8 row
    }
    __syncthreads();
    for (unsigned int j = t; j < n_pad; j += 512)
        col_fine[s + j] = sorted[j];

    // ---- fused init for this bucket's rows ----
    const int eb = b * ROWS_PER_BKT * DIM;
    for (int j = t * 4; j < ROWS_PER_BKT * DIM; j += 2048) {
        int i = eb + j;
        if (i >= n_total_elems) break;
        float4 v4 = (i < n_user_elems)
                       ? *(const float4*)(user_emb + i)
                       : *(const float4*)(item_emb + (i - n_user_elems));
        *(float4*)(acc_out + i)  = v4;
        *(float4*)(emb0_out + i) = v4;
        unsigned int deg = hist[j >> 6];
        float dv = 1.0f / sqrtf((float)(deg ? deg : 1u));
        curA[i >> 2] = pk_fp8_4(v4.x * dv, v4.y * dv, v4.z * dv, v4.w * dv);
    }
    // zero the sentinel row in BOTH ping-pong buffers (ws is poisoned)
    if (b == 0 && t < 16) {
        curA[(size_t)sent * 16 + t] = 0u;
        curB[(size_t)sent * 16 + t] = 0u;
    }
}

// Wave-per-row SpMM over pre-scaled fp8 state, padded 8-aligned CSR.
// Oct structure: oct o (8 lanes) owns 8-edge groups o, o+8, ... Each lane
// gathers 8 fp8 dims (dwordx2) per edge -> 8 edges/wave-instr, 64 edges
// per wave iteration. Packed f32x2 accumulate. Cols are byte offsets.
// Pads gather the zero sentinel row.
__global__ __launch_bounds__(256) void spmm_fine(
        const int* __restrict__ row_start, const int* __restrict__ row_end,
        const unsigned int* __restrict__ col_fine,  // byte offsets (col*64)
        const float* __restrict__ dinv,
        const unsigned int* __restrict__ cur,   // fp8x4, pre-scaled by dinv
        unsigned int* __restrict__ next,        // fp8x4, pre-scaled by dinv
        float* __restrict__ acc,
        float scale, int write_next, int n_rows) {
    const int lane = threadIdx.x & 63;
    const int r = (int)((blockIdx.x * blockDim.x + threadIdx.x) >> 6);
    if (r >= n_rows) return;
    const int o  = lane >> 3;                // oct 0..7
    const int ln = lane & 7;                 // dim slice: dims 8*ln..8*ln+7
    const int s = row_start[r];
    const int e = row_end[r];                // s,e multiples of 8 from bucket base
    const int ng = (e - s) >> 3;             // 8-edge groups

    // hoist streaming reads above the gather chain so they overlap it
    const float dr = dinv[r];
    float4 a0, a1;
    if (o == 0) {
        a0 = *(float4*)(acc + r * DIM + 8 * ln);
        a1 = *(float4*)(acc + r * DIM + 8 * ln + 4);
    }

    const char* curb = (const char*)cur;
    const int ln8 = ln * 8;
    f32x2 p0 = {0.f, 0.f}, p1 = {0.f, 0.f}, p2 = {0.f, 0.f}, p3 = {0.f, 0.f};
    for (int g = o; g < ng; g += 8) {
        const unsigned int* cp = col_fine + s + 8 * g;
        int4 ca = *(const int4*)cp;
        int4 cb = *(const int4*)(cp + 4);
        int c[8] = {ca.x, ca.y, ca.z, ca.w, cb.x, cb.y, cb.z, cb.w};
        uint2 u[8];
#pragma unroll
        for (int k = 0; k < 8; ++k)
            u[k] = *(const uint2*)(curb + c[k] + ln8);
#pragma unroll
        for (int k = 0; k < 8; ++k) {
            p0 += __builtin_amdgcn_cvt_pk_f32_fp8(u[k].x, false);
            p1 += __builtin_amdgcn_cvt_pk_f32_fp8(u[k].x, true);
            p2 += __builtin_amdgcn_cvt_pk_f32_fp8(u[k].y, false);
            p3 += __builtin_amdgcn_cvt_pk_f32_fp8(u[k].y, true);
        }
    }
    // butterfly reduce across octs (xor 8/16/32 preserves ln)
    float v0 = p0.x, v1 = p0.y, v2 = p1.x, v3 = p1.y;
    float v4 = p2.x, v5 = p2.y, v6 = p3.x, v7 = p3.y;
#pragma unroll
    for (int off = 8; off < 64; off <<= 1) {
        v0 += __shfl_xor(v0, off); v1 += __shfl_xor(v1, off);
        v2 += __shfl_xor(v2, off); v3 += __shfl_xor(v3, off);
        v4 += __shfl_xor(v4, off); v5 += __shfl_xor(v5, off);
        v6 += __shfl_xor(v6, off); v7 += __shfl_xor(v7, off);
    }
    if (o == 0) {
        float t0 = dr * v0, t1 = dr * v1, t2 = dr * v2, t3 = dr * v3;
        float t4 = dr * v4, t5 = dr * v5, t6 = dr * v6, t7 = dr * v7;
        if (write_next) {
            uint2 w;
            w.x = pk_fp8_4(dr * t0, dr * t1, dr * t2, dr * t3);
            w.y = pk_fp8_4(dr * t4, dr * t5, dr * t6, dr * t7);
            *(uint2*)(next + r * 16 + 2 * ln) = w;
        }
        a0.x = (a0.x + t0) * scale; a0.y = (a0.y + t1) * scale;
        a0.z = (a0.z + t2) * scale; a0.w = (a0.w + t3) * scale;
        a1.x = (a1.x + t4) * scale; a1.y = (a1.y + t5) * scale;
        a1.z = (a1.z + t6) * scale; a1.w = (a1.w + t7) * scale;
        *(float4*)(acc + r * DIM + 8 * ln)     = a0;
        *(float4*)(acc + r * DIM + 8 * ln + 4) = a1;
    }
}

extern "C" void kernel_launch(void* const* d_in, const int* in_sizes, int n_in,
                              void* d_out, int out_size, void* d_ws, size_t ws_size,
                              hipStream_t stream) {
    const float* user_emb = (const float*)d_in[0];
    const float* item_emb = (const float*)d_in[1];
    // d_in[2] = vals (recomputed as dinv[r]*dinv[c])
    const int*   row      = (const int*)d_in[3];
    const int*   col      = (const int*)d_in[4];

    const int n_user_elems  = in_sizes[0];                   // 3,200,000
    const int n_total_elems = n_user_elems + in_sizes[1];    // 6,400,000
    const int num_edges     = in_sizes[2];                   // 3,200,000
    const int n_rows        = n_total_elems / DIM;           // 100,000
    const int nb            = (n_rows + ROWS_PER_BKT - 1) / ROWS_PER_BKT; // 391
    const unsigned int sent = (unsigned int)n_rows;          // zero sentinel node

    float* out_mean = (float*)d_out;
    float* out_emb0 = out_mean + n_total_elems;

    // workspace (~49MB): curA/B fp8 (n_rows+1 rows) | ebuf | col_fine | meta
    unsigned int* curA       = (unsigned int*)d_ws;
    unsigned int* curB       = curA + (size_t)(n_rows + 1) * 16;
    unsigned int* ebuf       = curB + (size_t)(n_rows + 1) * 16;
    unsigned int* col_fine   = ebuf + (size_t)nb * BKT_CAP;
    int*          row_startp = (int*)(col_fine + (size_t)nb * BKT_CAP);
    int*          row_endp   = row_startp + n_rows;
    float*        dinv       = (float*)(row_endp + n_rows);
    int*          cursor     = (int*)(dinv + n_rows);

    hipMemsetAsync(cursor, 0, nb * sizeof(int), stream);
    scatter_agg<<<(num_edges + CHUNK - 1) / CHUNK, 512, 0, stream>>>(
        (const int4*)row, (const int4*)col, cursor, ebuf, num_edges, nb);
    bucket_to_csr<<<nb, 512, 0, stream>>>(ebuf, cursor, col_fine, row_startp,
                                          row_endp, dinv, user_emb, item_emb,
                                          out_mean, out_emb0, curA, curB,
                                          n_user_elems, n_total_elems, n_rows,
                                          sent);

    const int spmm_blocks = (n_rows * 64 + 255) / 256;       // wave per row
    constexpr int STAGES = 3;
    for (int s = 0; s < STAGES; ++s) {
        int last = (s == STAGES - 1);
        float scale = last ? 1.0f / (STAGES + 1) : 1.0f;
        spmm_fine<<<spmm_blocks, 256, 0, stream>>>(row_startp, row_endp,
                                                   col_fine, dinv, curA, curB,
                                                   out_mean, scale, !last,
                                                   n_rows);
        unsigned int* t = curA; curA = curB; curB = t;
    }
}

// Round 3
// 259.758 us; speedup vs baseline: 1.1020x; 1.1020x over previous
//
#include <hip/hip_runtime.h>

// LightGCN 3-stage propagation — round 10: revert to r8 quarter-structured
// SpMM + real packed accumulate (inline-asm v_pk_add_f32).
//
// Evidence trail:
//  r1: edge atomics -> 819MB/stage write-through (666us/stage).
//  r2: fine CSR spmm ~280us/stage (f32); scattered CSR build 297us.
//  r3: LDS-tile spmm latency-starved; coarse bucket build fast.
//  r4: bucket->LDS->CSR + wave-per-row bf16 spmm: 152us/stage.
//  r5: 16-edge batched gathers + prescaled state: 67us/stage (byte-bound).
//  r6: fp8 e4m3 state: 51us/stage.
//  r7: fused build + padded 8-aligned CSR with sentinel row: 278us total.
//  r8: unified strided spmm loop + wave scans in build: 261us total.
//      spmm: 41.5us/stage, VALU 58%, HBM 29%, occ 63%.
//  r9: oct restructure REGRESSED (52us/stage): f32x2 += lowered to scalar
//      adds (no v_pk_add_f32), and 8-val x 3-step reduction tripled the
//      per-row tail. Lesson: packed ops must be forced via asm; keep the
//      reduction at 4 vals x 2 steps.
//  r10: r8 structure + asm v_pk_add_f32 (32 scalar adds -> 16 pk adds per
//      32 edges), 4 accumulators to halve chain depth, byte-offset cols.
//      ~50 wave-instrs per 32 edges vs r8's ~66.

constexpr int DIM = 64;
constexpr int ROWS_PER_BKT = 256;
constexpr int BKT_CAP = 11264;      // raw max ~8.7k + pad up to 256*7 -> 10.5k
constexpr int CHUNK = 4096;
constexpr int SCAN_N = 512;

using f32x2 = __attribute__((ext_vector_type(2))) float;

__device__ inline unsigned int pk_fp8_4(float a, float b, float c, float d) {
    int v = __builtin_amdgcn_cvt_pk_fp8_f32(a, b, 0, false);
    v = __builtin_amdgcn_cvt_pk_fp8_f32(c, d, v, true);
    return (unsigned int)v;
}

__device__ inline f32x2 pk_add(f32x2 a, f32x2 b) {
    f32x2 d;
    asm("v_pk_add_f32 %0, %1, %2" : "=v"(d) : "v"(a), "v"(b));
    return d;
}

// Block-aggregated coarse scatter into 391 row-buckets (512 threads,
// 8 edges/thread). Ranks relative to cursor[]==0 (memset).
__global__ __launch_bounds__(512) void scatter_agg(
        const int4* __restrict__ row4, const int4* __restrict__ col4,
        int* __restrict__ cursor, unsigned int* __restrict__ ebuf,
        int num_edges, int nb) {
    __shared__ unsigned int cnt[SCAN_N];
    __shared__ unsigned int orig[SCAN_N];
    __shared__ unsigned int bbase[SCAN_N];
    __shared__ unsigned int wsum[8];
    __shared__ unsigned int stage[CHUNK];
    __shared__ unsigned int dsts[CHUNK];
    const int t = threadIdx.x;

    cnt[t] = 0;
    __syncthreads();

    unsigned int pk[8];
    unsigned short bk[8], rk[8];
    const int base4 = blockIdx.x * (CHUNK / 4);
#pragma unroll
    for (int k = 0; k < 2; ++k) {
        int e4 = base4 + k * 512 + t;            // num_edges % 4 == 0
        if (e4 * 4 < num_edges) {
            int4 rr = row4[e4];
            int4 cc = col4[e4];
            int rs[4] = {rr.x, rr.y, rr.z, rr.w};
            int cs[4] = {cc.x, cc.y, cc.z, cc.w};
#pragma unroll
            for (int m = 0; m < 4; ++m) {
                int b = rs[m] >> 8;
                unsigned int rank = atomicAdd(&cnt[b], 1u);
                pk[k * 4 + m] = ((unsigned)(rs[m] & 255) << 17) | (unsigned)cs[m];
                bk[k * 4 + m] = (unsigned short)b;
                rk[k * 4 + m] = (unsigned short)rank;
            }
        } else {
#pragma unroll
            for (int m = 0; m < 4; ++m) bk[k * 4 + m] = 0xFFFFu;
        }
    }
    __syncthreads();

    // wave-level inclusive scan of cnt[] (2 barriers total)
    unsigned int myv = cnt[t];
    orig[t] = myv;
    unsigned int v = myv;
#pragma unroll
    for (int off = 1; off < 64; off <<= 1) {
        unsigned int nv = __shfl_up(v, off);
        if ((t & 63) >= off) v += nv;
    }
    if ((t & 63) == 63) wsum[t >> 6] = v;
    // per-bucket global base: independent of the scan, issue now
    if (t < nb && myv > 0)
        bbase[t] = (unsigned int)(t * BKT_CAP +
                                  atomicAdd(&cursor[t], (int)myv));
    __syncthreads();
    {
        unsigned int addv = 0;
        const int wid = t >> 6;
#pragma unroll
        for (int w = 0; w < 7; ++w)
            if (w < wid) addv += wsum[w];
        cnt[t] = v + addv;                       // inclusive scan result
    }
    __syncthreads();

#pragma unroll
    for (int k = 0; k < 8; ++k) {
        if (bk[k] != 0xFFFFu) {
            int b = bk[k];
            unsigned int ofs = (cnt[b] - orig[b]) + rk[k];
            stage[ofs] = pk[k];
            dsts[ofs] = bbase[b] + rk[k];
        }
    }
    __syncthreads();
    unsigned int total = cnt[SCAN_N - 1];
    for (unsigned int j = t; j < total; j += 512)
        ebuf[dsts[j]] = stage[j];
}

// One 512-thread block per bucket: hist -> padded scan -> permute into
// 8-aligned padded CSR (pad slots = sentinel node) -> coalesced write-out.
// col_fine stores BYTE offsets (col*64) for the fp8 state gather.
// FUSED epilogue: init acc/emb0/curA for this bucket's 256 rows using the
// in-LDS degrees.
__global__ __launch_bounds__(512) void bucket_to_csr(
        const unsigned int* __restrict__ ebuf, const int* __restrict__ cursor,
        unsigned int* __restrict__ col_fine,
        int* __restrict__ row_start, int* __restrict__ row_end,
        float* __restrict__ dinv,
        const float* __restrict__ user_emb, const float* __restrict__ item_emb,
        float* __restrict__ acc_out, float* __restrict__ emb0_out,
        unsigned int* __restrict__ curA, unsigned int* __restrict__ curB,
        int n_user_elems, int n_total_elems, int n_rows, unsigned int sent) {
    __shared__ unsigned int hist[ROWS_PER_BKT];
    __shared__ unsigned int scanv[ROWS_PER_BKT];
    __shared__ unsigned int curl[ROWS_PER_BKT];
    __shared__ unsigned int wsumB[4];
    __shared__ unsigned int sorted[BKT_CAP];
    const int t = threadIdx.x;
    const int b = blockIdx.x;
    const int s = b * BKT_CAP;
    const int n = cursor[b];

    if (t < ROWS_PER_BKT) hist[t] = 0;
    __syncthreads();
    for (int j = t; j < n; j += 512)
        atomicAdd(&hist[ebuf[s + j] >> 17], 1u);
    __syncthreads();

    // wave-level inclusive scan of padded degrees (2 barriers total)
    unsigned int pdeg = 0;
    if (t < ROWS_PER_BKT) pdeg = (hist[t] + 7u) & ~7u;
    unsigned int v = pdeg;
#pragma unroll
    for (int off = 1; off < 64; off <<= 1) {
        unsigned int nv = __shfl_up(v, off);
        if ((t & 63) >= off) v += nv;
    }
    if (t < ROWS_PER_BKT && (t & 63) == 63) wsumB[t >> 6] = v;
    __syncthreads();
    if (t < ROWS_PER_BKT) {
        unsigned int addv = 0;
        const int wid = t >> 6;
#pragma unroll
        for (int w = 0; w < 3; ++w)
            if (w < wid) addv += wsumB[w];
        unsigned int incl = v + addv;
        scanv[t] = incl;
        unsigned int excl = incl - pdeg;
        curl[t] = excl;
        int r = b * ROWS_PER_BKT + t;
        if (r < n_rows) {
            unsigned int deg = hist[t];
            dinv[r] = 1.0f / sqrtf((float)(deg ? deg : 1u));
            row_start[r] = s + (int)excl;
            row_end[r]   = s + (int)(excl + pdeg);
        }
    }
    __syncthreads();
    unsigned int n_pad = scanv[ROWS_PER_BKT - 1];
    // prefill pad slots with sentinel byte offset
    const unsigned int sentb = sent << 6;
    for (unsigned int j = t; j < n_pad; j += 512) sorted[j] = sentb;
    __syncthreads();
    for (int j = t; j < n; j += 512) {
        unsigned int pk = ebuf[s + j];
        unsigned int p = atomicAdd(&curl[pk >> 17], 1u);
        sorted[p] = (pk & 0x1FFFFu) << 6;        // byte offset of fp8 row
    }
    __syncthreads();
    for (unsigned int j = t; j < n_pad; j += 512)
        col_fine[s + j] = sorted[j];

    // ---- fused init for this bucket's rows ----
    const int eb = b * ROWS_PER_BKT * DIM;
    for (int j = t * 4; j < ROWS_PER_BKT * DIM; j += 2048) {
        int i = eb + j;
        if (i >= n_total_elems) break;
        float4 v4 = (i < n_user_elems)
                       ? *(const float4*)(user_emb + i)
                       : *(const float4*)(item_emb + (i - n_user_elems));
        *(float4*)(acc_out + i)  = v4;
        *(float4*)(emb0_out + i) = v4;
        unsigned int deg = hist[j >> 6];
        float dv = 1.0f / sqrtf((float)(deg ? deg : 1u));
        curA[i >> 2] = pk_fp8_4(v4.x * dv, v4.y * dv, v4.z * dv, v4.w * dv);
    }
    // zero the sentinel row in BOTH ping-pong buffers (ws is poisoned)
    if (b == 0 && t < 16) {
        curA[(size_t)sent * 16 + t] = 0u;
        curB[(size_t)sent * 16 + t] = 0u;
    }
}

// Wave-per-row SpMM over pre-scaled fp8 state, padded 8-aligned CSR.
// r8 quarter structure: quarter q owns 8-edge groups q, q+4, ... Each
// gather instr covers 4 rows x 64B (dword per lane). Packed accumulate
// via asm v_pk_add_f32 (4 accumulators, even/odd k). Cols = byte offsets.
// Pads gather the zero sentinel row.
__global__ __launch_bounds__(256) void spmm_fine(
        const int* __restrict__ row_start, const int* __restrict__ row_end,
        const unsigned int* __restrict__ col_fine,  // byte offsets (col*64)
        const float* __restrict__ dinv,
        const unsigned int* __restrict__ cur,   // fp8x4, pre-scaled by dinv
        unsigned int* __restrict__ next,        // fp8x4, pre-scaled by dinv
        float* __restrict__ acc,
        float scale, int write_next, int n_rows) {
    const int lane = threadIdx.x & 63;
    const int r = (int)((blockIdx.x * blockDim.x + threadIdx.x) >> 6);
    if (r >= n_rows) return;
    const int q  = lane >> 4;                // quarter 0..3
    const int ln = lane & 15;                // dim group (4 dims)
    const int s = row_start[r];
    const int e = row_end[r];                // s,e multiples of 8 from bucket base
    const int ng = (e - s) >> 3;             // 8-edge groups

    // hoist streaming reads above the gather chain so they overlap it
    const float dr = dinv[r];
    float4 a;
    if (q == 0) a = *(float4*)(acc + r * DIM + 4 * ln);

    const char* curb = (const char*)cur;
    const int ln4 = ln * 4;
    f32x2 pA_lo = {0.f, 0.f}, pA_hi = {0.f, 0.f};   // even k
    f32x2 pB_lo = {0.f, 0.f}, pB_hi = {0.f, 0.f};   // odd k
    for (int g = q; g < ng; g += 4) {
        const unsigned int* cp = col_fine + s + 8 * g;
        int4 ca = *(const int4*)cp;
        int4 cb = *(const int4*)(cp + 4);
        int c[8] = {ca.x, ca.y, ca.z, ca.w, cb.x, cb.y, cb.z, cb.w};
        unsigned int u[8];
#pragma unroll
        for (int k = 0; k < 8; ++k)
            u[k] = *(const unsigned int*)(curb + c[k] + ln4);
#pragma unroll
        for (int k = 0; k < 8; k += 2) {
            pA_lo = pk_add(pA_lo, __builtin_amdgcn_cvt_pk_f32_fp8(u[k], false));
            pA_hi = pk_add(pA_hi, __builtin_amdgcn_cvt_pk_f32_fp8(u[k], true));
            pB_lo = pk_add(pB_lo, __builtin_amdgcn_cvt_pk_f32_fp8(u[k + 1], false));
            pB_hi = pk_add(pB_hi, __builtin_amdgcn_cvt_pk_f32_fp8(u[k + 1], true));
        }
    }
    f32x2 plo = pk_add(pA_lo, pB_lo);
    f32x2 phi = pk_add(pA_hi, pB_hi);
    float s0 = plo.x, s1 = plo.y, s2 = phi.x, s3 = phi.y;
    // reduce across quarters
    s0 += __shfl_xor(s0, 16); s0 += __shfl_xor(s0, 32);
    s1 += __shfl_xor(s1, 16); s1 += __shfl_xor(s1, 32);
    s2 += __shfl_xor(s2, 16); s2 += __shfl_xor(s2, 32);
    s3 += __shfl_xor(s3, 16); s3 += __shfl_xor(s3, 32);
    float t0 = dr * s0, t1 = dr * s1, t2 = dr * s2, t3 = dr * s3;
    if (q == 0) {
        if (write_next)
            next[r * 16 + ln] = pk_fp8_4(dr * t0, dr * t1, dr * t2, dr * t3);
        a.x = (a.x + t0) * scale; a.y = (a.y + t1) * scale;
        a.z = (a.z + t2) * scale; a.w = (a.w + t3) * scale;
        *(float4*)(acc + r * DIM + 4 * ln) = a;
    }
}

extern "C" void kernel_launch(void* const* d_in, const int* in_sizes, int n_in,
                              void* d_out, int out_size, void* d_ws, size_t ws_size,
                              hipStream_t stream) {
    const float* user_emb = (const float*)d_in[0];
    const float* item_emb = (const float*)d_in[1];
    // d_in[2] = vals (recomputed as dinv[r]*dinv[c])
    const int*   row      = (const int*)d_in[3];
    const int*   col      = (const int*)d_in[4];

    const int n_user_elems  = in_sizes[0];                   // 3,200,000
    const int n_total_elems = n_user_elems + in_sizes[1];    // 6,400,000
    const int num_edges     = in_sizes[2];                   // 3,200,000
    const int n_rows        = n_total_elems / DIM;           // 100,000
    const int nb            = (n_rows + ROWS_PER_BKT - 1) / ROWS_PER_BKT; // 391
    const unsigned int sent = (unsigned int)n_rows;          // zero sentinel node

    float* out_mean = (float*)d_out;
    float* out_emb0 = out_mean + n_total_elems;

    // workspace (~49MB): curA/B fp8 (n_rows+1 rows) | ebuf | col_fine | meta
    unsigned int* curA       = (unsigned int*)d_ws;
    unsigned int* curB       = curA + (size_t)(n_rows + 1) * 16;
    unsigned int* ebuf       = curB + (size_t)(n_rows + 1) * 16;
    unsigned int* col_fine   = ebuf + (size_t)nb * BKT_CAP;
    int*          row_startp = (int*)(col_fine + (size_t)nb * BKT_CAP);
    int*          row_endp   = row_startp + n_rows;
    float*        dinv       = (float*)(row_endp + n_rows);
    int*          cursor     = (int*)(dinv + n_rows);

    hipMemsetAsync(cursor, 0, nb * sizeof(int), stream);
    scatter_agg<<<(num_edges + CHUNK - 1) / CHUNK, 512, 0, stream>>>(
        (const int4*)row, (const int4*)col, cursor, ebuf, num_edges, nb);
    bucket_to_csr<<<nb, 512, 0, stream>>>(ebuf, cursor, col_fine, row_startp,
                                          row_endp, dinv, user_emb, item_emb,
                                          out_mean, out_emb0, curA, curB,
                                          n_user_elems, n_total_elems, n_rows,
                                          sent);

    const int spmm_blocks = (n_rows * 64 + 255) / 256;       // wave per row
    constexpr int STAGES = 3;
    for (int s = 0; s < STAGES; ++s) {
        int last = (s == STAGES - 1);
        float scale = last ? 1.0f / (STAGES + 1) : 1.0f;
        spmm_fine<<<spmm_blocks, 256, 0, stream>>>(row_startp, row_endp,
                                                   col_fine, dinv, curA, curB,
                                                   out_mean, scale, !last,
                                                   n_rows);
        unsigned int* t = curA; curA = curB; curB = t;
    }
}

// Round 4
// 247.709 us; speedup vs baseline: 1.1556x; 1.0486x over previous
//
#include <hip/hip_runtime.h>

// LightGCN 3-stage propagation — round 11: 4-rows-per-wave SpMM
// (quarter-per-row, zero-shuffle tail, 4x per-row overhead amortization).
//
// Evidence trail:
//  r1: edge atomics -> 819MB/stage write-through (666us/stage).
//  r2: fine CSR spmm ~280us/stage (f32); scattered CSR build 297us.
//  r3: LDS-tile spmm latency-starved; coarse bucket build fast.
//  r4: bucket->LDS->CSR + wave-per-row bf16 spmm: 152us/stage.
//  r5: 16-edge batched gathers + prescaled state: 67us/stage (byte-bound).
//  r6: fp8 e4m3 state: 51us/stage.
//  r7: fused build + padded 8-aligned CSR with sentinel row: 278us total.
//  r8: unified strided spmm loop + wave scans in build: 261us total.
//      spmm: 41.5us/stage, VALU 58%, HBM 29%, occ 63%.
//  r9: oct restructure REGRESSED (52us): bigger reduction tail + no pk_add.
//  r10: asm v_pk_add_f32 in r8 structure: 259.8us — only -1us. FALSIFIER:
//      -24% main-loop VALU gave ~0 => main loop is NOT the cost. Per-SIMD
//      arithmetic: ~1000cy/row total, ~585cy/row VALU-busy, main loop only
//      ~180cy => per-row FIXED cost dominates (meta, 16-op shuffle tail,
//      masked store path, prologue) + unhidden 3-deep latency chain.
//  r11: quarter-per-row, 4 rows/wave: same main-loop instr count, but
//      meta/store/epilogue amortized 4x, shuffle tail deleted (lane holds
//      final partials), stores full-wave coalesced, 8 gathers in flight
//      even for short rows. Accepts ~30% masked-issue waste at max(ng).

constexpr int DIM = 64;
constexpr int ROWS_PER_BKT = 256;
constexpr int BKT_CAP = 11264;      // raw max ~8.7k + pad up to 256*7 -> 10.5k
constexpr int CHUNK = 4096;
constexpr int SCAN_N = 512;

using f32x2 = __attribute__((ext_vector_type(2))) float;

__device__ inline unsigned int pk_fp8_4(float a, float b, float c, float d) {
    int v = __builtin_amdgcn_cvt_pk_fp8_f32(a, b, 0, false);
    v = __builtin_amdgcn_cvt_pk_fp8_f32(c, d, v, true);
    return (unsigned int)v;
}

__device__ inline f32x2 pk_add(f32x2 a, f32x2 b) {
    f32x2 d;
    asm("v_pk_add_f32 %0, %1, %2" : "=v"(d) : "v"(a), "v"(b));
    return d;
}

// Block-aggregated coarse scatter into 391 row-buckets (512 threads,
// 8 edges/thread). Ranks relative to cursor[]==0 (memset).
__global__ __launch_bounds__(512) void scatter_agg(
        const int4* __restrict__ row4, const int4* __restrict__ col4,
        int* __restrict__ cursor, unsigned int* __restrict__ ebuf,
        int num_edges, int nb) {
    __shared__ unsigned int cnt[SCAN_N];
    __shared__ unsigned int orig[SCAN_N];
    __shared__ unsigned int bbase[SCAN_N];
    __shared__ unsigned int wsum[8];
    __shared__ unsigned int stage[CHUNK];
    __shared__ unsigned int dsts[CHUNK];
    const int t = threadIdx.x;

    cnt[t] = 0;
    __syncthreads();

    unsigned int pk[8];
    unsigned short bk[8], rk[8];
    const int base4 = blockIdx.x * (CHUNK / 4);
#pragma unroll
    for (int k = 0; k < 2; ++k) {
        int e4 = base4 + k * 512 + t;            // num_edges % 4 == 0
        if (e4 * 4 < num_edges) {
            int4 rr = row4[e4];
            int4 cc = col4[e4];
            int rs[4] = {rr.x, rr.y, rr.z, rr.w};
            int cs[4] = {cc.x, cc.y, cc.z, cc.w};
#pragma unroll
            for (int m = 0; m < 4; ++m) {
                int b = rs[m] >> 8;
                unsigned int rank = atomicAdd(&cnt[b], 1u);
                pk[k * 4 + m] = ((unsigned)(rs[m] & 255) << 17) | (unsigned)cs[m];
                bk[k * 4 + m] = (unsigned short)b;
                rk[k * 4 + m] = (unsigned short)rank;
            }
        } else {
#pragma unroll
            for (int m = 0; m < 4; ++m) bk[k * 4 + m] = 0xFFFFu;
        }
    }
    __syncthreads();

    // wave-level inclusive scan of cnt[] (2 barriers total)
    unsigned int myv = cnt[t];
    orig[t] = myv;
    unsigned int v = myv;
#pragma unroll
    for (int off = 1; off < 64; off <<= 1) {
        unsigned int nv = __shfl_up(v, off);
        if ((t & 63) >= off) v += nv;
    }
    if ((t & 63) == 63) wsum[t >> 6] = v;
    // per-bucket global base: independent of the scan, issue now
    if (t < nb && myv > 0)
        bbase[t] = (unsigned int)(t * BKT_CAP +
                                  atomicAdd(&cursor[t], (int)myv));
    __syncthreads();
    {
        unsigned int addv = 0;
        const int wid = t >> 6;
#pragma unroll
        for (int w = 0; w < 7; ++w)
            if (w < wid) addv += wsum[w];
        cnt[t] = v + addv;                       // inclusive scan result
    }
    __syncthreads();

#pragma unroll
    for (int k = 0; k < 8; ++k) {
        if (bk[k] != 0xFFFFu) {
            int b = bk[k];
            unsigned int ofs = (cnt[b] - orig[b]) + rk[k];
            stage[ofs] = pk[k];
            dsts[ofs] = bbase[b] + rk[k];
        }
    }
    __syncthreads();
    unsigned int total = cnt[SCAN_N - 1];
    for (unsigned int j = t; j < total; j += 512)
        ebuf[dsts[j]] = stage[j];
}

// One 512-thread block per bucket: hist -> padded scan -> permute into
// 8-aligned padded CSR (pad slots = sentinel node) -> coalesced write-out.
// col_fine stores BYTE offsets (col*64) for the fp8 state gather.
// FUSED epilogue: init acc/emb0/curA for this bucket's 256 rows using the
// in-LDS degrees.
__global__ __launch_bounds__(512) void bucket_to_csr(
        const unsigned int* __restrict__ ebuf, const int* __restrict__ cursor,
        unsigned int* __restrict__ col_fine,
        int* __restrict__ row_start, int* __restrict__ row_end,
        float* __restrict__ dinv,
        const float* __restrict__ user_emb, const float* __restrict__ item_emb,
        float* __restrict__ acc_out, float* __restrict__ emb0_out,
        unsigned int* __restrict__ curA, unsigned int* __restrict__ curB,
        int n_user_elems, int n_total_elems, int n_rows, unsigned int sent) {
    __shared__ unsigned int hist[ROWS_PER_BKT];
    __shared__ unsigned int scanv[ROWS_PER_BKT];
    __shared__ unsigned int curl[ROWS_PER_BKT];
    __shared__ unsigned int wsumB[4];
    __shared__ unsigned int sorted[BKT_CAP];
    const int t = threadIdx.x;
    const int b = blockIdx.x;
    const int s = b * BKT_CAP;
    const int n = cursor[b];

    if (t < ROWS_PER_BKT) hist[t] = 0;
    __syncthreads();
    for (int j = t; j < n; j += 512)
        atomicAdd(&hist[ebuf[s + j] >> 17], 1u);
    __syncthreads();

    // wave-level inclusive scan of padded degrees (2 barriers total)
    unsigned int pdeg = 0;
    if (t < ROWS_PER_BKT) pdeg = (hist[t] + 7u) & ~7u;
    unsigned int v = pdeg;
#pragma unroll
    for (int off = 1; off < 64; off <<= 1) {
        unsigned int nv = __shfl_up(v, off);
        if ((t & 63) >= off) v += nv;
    }
    if (t < ROWS_PER_BKT && (t & 63) == 63) wsumB[t >> 6] = v;
    __syncthreads();
    if (t < ROWS_PER_BKT) {
        unsigned int addv = 0;
        const int wid = t >> 6;
#pragma unroll
        for (int w = 0; w < 3; ++w)
            if (w < wid) addv += wsumB[w];
        unsigned int incl = v + addv;
        scanv[t] = incl;
        unsigned int excl = incl - pdeg;
        curl[t] = excl;
        int r = b * ROWS_PER_BKT + t;
        if (r < n_rows) {
            unsigned int deg = hist[t];
            dinv[r] = 1.0f / sqrtf((float)(deg ? deg : 1u));
            row_start[r] = s + (int)excl;
            row_end[r]   = s + (int)(excl + pdeg);
        }
    }
    __syncthreads();
    unsigned int n_pad = scanv[ROWS_PER_BKT - 1];
    // prefill pad slots with sentinel byte offset
    const unsigned int sentb = sent << 6;
    for (unsigned int j = t; j < n_pad; j += 512) sorted[j] = sentb;
    __syncthreads();
    for (int j = t; j < n; j += 512) {
        unsigned int pk = ebuf[s + j];
        unsigned int p = atomicAdd(&curl[pk >> 17], 1u);
        sorted[p] = (pk & 0x1FFFFu) << 6;        // byte offset of fp8 row
    }
    __syncthreads();
    for (unsigned int j = t; j < n_pad; j += 512)
        col_fine[s + j] = sorted[j];

    // ---- fused init for this bucket's rows ----
    const int eb = b * ROWS_PER_BKT * DIM;
    for (int j = t * 4; j < ROWS_PER_BKT * DIM; j += 2048) {
        int i = eb + j;
        if (i >= n_total_elems) break;
        float4 v4 = (i < n_user_elems)
                       ? *(const float4*)(user_emb + i)
                       : *(const float4*)(item_emb + (i - n_user_elems));
        *(float4*)(acc_out + i)  = v4;
        *(float4*)(emb0_out + i) = v4;
        unsigned int deg = hist[j >> 6];
        float dv = 1.0f / sqrtf((float)(deg ? deg : 1u));
        curA[i >> 2] = pk_fp8_4(v4.x * dv, v4.y * dv, v4.z * dv, v4.w * dv);
    }
    // zero the sentinel row in BOTH ping-pong buffers (ws is poisoned)
    if (b == 0 && t < 16) {
        curA[(size_t)sent * 16 + t] = 0u;
        curB[(size_t)sent * 16 + t] = 0u;
    }
}

// 4-rows-per-wave SpMM over pre-scaled fp8 state, padded 8-aligned CSR.
// Quarter q (16 lanes) owns row wave*4+q entirely; lane ln holds dims
// 4ln..4ln+3. Per 8-edge group: 2 int4 col loads (quarter-uniform) + 8
// dword gathers in flight + cvt/pk_add. NO cross-lane reduction tail —
// each lane finishes holding its dims' final partials; all 64 lanes store
// (fully coalesced: 4 consecutive rows per wave). Meta/epilogue amortized
// 4x vs wave-per-row. Pads gather the zero sentinel row.
__global__ __launch_bounds__(256) void spmm_fine(
        const int* __restrict__ row_start, const int* __restrict__ row_end,
        const unsigned int* __restrict__ col_fine,  // byte offsets (col*64)
        const float* __restrict__ dinv,
        const unsigned int* __restrict__ cur,   // fp8x4, pre-scaled by dinv
        unsigned int* __restrict__ next,        // fp8x4, pre-scaled by dinv
        float* __restrict__ acc,
        float scale, int write_next, int n_rows) {
    const int lane = threadIdx.x & 63;
    const int wave = (int)((blockIdx.x * blockDim.x + threadIdx.x) >> 6);
    const int q  = lane >> 4;                // quarter 0..3
    const int ln = lane & 15;                // dim group (4 dims)
    const int r = wave * 4 + q;              // this quarter's row
    const bool valid = (r < n_rows);

    int s = 0, e = 0;
    float dr = 0.f;
    float4 a = {0.f, 0.f, 0.f, 0.f};
    if (valid) {
        s = row_start[r];
        e = row_end[r];
        dr = dinv[r];
        a = *(const float4*)(acc + r * DIM + 4 * ln);
    }
    int ng = (e - s) >> 3;                   // 8-edge groups for this row

    // wave-max group count (2 shuffles, once per 4 rows)
    int mg = ng;
    mg = max(mg, __shfl_xor(mg, 16));
    mg = max(mg, __shfl_xor(mg, 32));

    const char* curb = (const char*)cur;
    const int ln4 = ln * 4;
    f32x2 pA_lo = {0.f, 0.f}, pA_hi = {0.f, 0.f};   // even k
    f32x2 pB_lo = {0.f, 0.f}, pB_hi = {0.f, 0.f};   // odd k
    for (int g = 0; g < mg; ++g) {
        if (g < ng) {                        // uniform within each quarter
            const unsigned int* cp = col_fine + s + 8 * g;
            int4 ca = *(const int4*)cp;
            int4 cb = *(const int4*)(cp + 4);
            int c[8] = {ca.x, ca.y, ca.z, ca.w, cb.x, cb.y, cb.z, cb.w};
            unsigned int u[8];
#pragma unroll
            for (int k = 0; k < 8; ++k)
                u[k] = *(const unsigned int*)(curb + c[k] + ln4);
#pragma unroll
            for (int k = 0; k < 8; k += 2) {
                pA_lo = pk_add(pA_lo, __builtin_amdgcn_cvt_pk_f32_fp8(u[k], false));
                pA_hi = pk_add(pA_hi, __builtin_amdgcn_cvt_pk_f32_fp8(u[k], true));
                pB_lo = pk_add(pB_lo, __builtin_amdgcn_cvt_pk_f32_fp8(u[k + 1], false));
                pB_hi = pk_add(pB_hi, __builtin_amdgcn_cvt_pk_f32_fp8(u[k + 1], true));
            }
        }
    }
    f32x2 plo = pk_add(pA_lo, pB_lo);
    f32x2 phi = pk_add(pA_hi, pB_hi);
    if (valid) {
        float t0 = dr * plo.x, t1 = dr * plo.y;
        float t2 = dr * phi.x, t3 = dr * phi.y;
        if (write_next)
            next[r * 16 + ln] = pk_fp8_4(dr * t0, dr * t1, dr * t2, dr * t3);
        a.x = (a.x + t0) * scale; a.y = (a.y + t1) * scale;
        a.z = (a.z + t2) * scale; a.w = (a.w + t3) * scale;
        *(float4*)(acc + r * DIM + 4 * ln) = a;
    }
}

extern "C" void kernel_launch(void* const* d_in, const int* in_sizes, int n_in,
                              void* d_out, int out_size, void* d_ws, size_t ws_size,
                              hipStream_t stream) {
    const float* user_emb = (const float*)d_in[0];
    const float* item_emb = (const float*)d_in[1];
    // d_in[2] = vals (recomputed as dinv[r]*dinv[c])
    const int*   row      = (const int*)d_in[3];
    const int*   col      = (const int*)d_in[4];

    const int n_user_elems  = in_sizes[0];                   // 3,200,000
    const int n_total_elems = n_user_elems + in_sizes[1];    // 6,400,000
    const int num_edges     = in_sizes[2];                   // 3,200,000
    const int n_rows        = n_total_elems / DIM;           // 100,000
    const int nb            = (n_rows + ROWS_PER_BKT - 1) / ROWS_PER_BKT; // 391
    const unsigned int sent = (unsigned int)n_rows;          // zero sentinel node

    float* out_mean = (float*)d_out;
    float* out_emb0 = out_mean + n_total_elems;

    // workspace (~49MB): curA/B fp8 (n_rows+1 rows) | ebuf | col_fine | meta
    unsigned int* curA       = (unsigned int*)d_ws;
    unsigned int* curB       = curA + (size_t)(n_rows + 1) * 16;
    unsigned int* ebuf       = curB + (size_t)(n_rows + 1) * 16;
    unsigned int* col_fine   = ebuf + (size_t)nb * BKT_CAP;
    int*          row_startp = (int*)(col_fine + (size_t)nb * BKT_CAP);
    int*          row_endp   = row_startp + n_rows;
    float*        dinv       = (float*)(row_endp + n_rows);
    int*          cursor     = (int*)(dinv + n_rows);

    hipMemsetAsync(cursor, 0, nb * sizeof(int), stream);
    scatter_agg<<<(num_edges + CHUNK - 1) / CHUNK, 512, 0, stream>>>(
        (const int4*)row, (const int4*)col, cursor, ebuf, num_edges, nb);
    bucket_to_csr<<<nb, 512, 0, stream>>>(ebuf, cursor, col_fine, row_startp,
                                          row_endp, dinv, user_emb, item_emb,
                                          out_mean, out_emb0, curA, curB,
                                          n_user_elems, n_total_elems, n_rows,
                                          sent);

    // 4 rows per wave -> 16 rows per 256-thread block
    const int spmm_blocks = (n_rows + 15) / 16;
    constexpr int STAGES = 3;
    for (int s = 0; s < STAGES; ++s) {
        int last = (s == STAGES - 1);
        float scale = last ? 1.0f / (STAGES + 1) : 1.0f;
        spmm_fine<<<spmm_blocks, 256, 0, stream>>>(row_startp, row_endp,
                                                   col_fine, dinv, curA, curB,
                                                   out_mean, scale, !last,
                                                   n_rows);
        unsigned int* t = curA; curA = curB; curB = t;
    }
}